// Round 15
// baseline (679.717 us; speedup 1.0000x reference)
//
#include <hip/hip_runtime.h>

#define N_NODES 12288
#define N_EDGES 393216
#define DIN 512
#define DH 256
#define DZ 64
#define NBA 2048

typedef __bf16 bf16x8 __attribute__((ext_vector_type(8)));
typedef float f32x4 __attribute__((ext_vector_type(4)));
typedef unsigned short u16x8 __attribute__((ext_vector_type(8)));

static __device__ __forceinline__ unsigned short f2bf(float f) {
    unsigned int u = __float_as_uint(f);
    unsigned int r = (u + 0x7fffu + ((u >> 16) & 1u)) >> 16;
    return (unsigned short)r;
}
static __device__ __forceinline__ float bf2f(unsigned short u) {
    return __uint_as_float((unsigned int)u << 16);
}

// R11-verified grid barrier: relaxed spin, single acquire after exit.
static __device__ __forceinline__ void gridbar(int* bar, int p, int nb) {
    __syncthreads();
    if (threadIdx.x == 0) {
        __hip_atomic_fetch_add(&bar[p], 1, __ATOMIC_RELEASE, __HIP_MEMORY_SCOPE_AGENT);
        while (__hip_atomic_load(&bar[p], __ATOMIC_RELAXED, __HIP_MEMORY_SCOPE_AGENT) < nb)
            __builtin_amdgcn_s_sleep(8);
        (void)__hip_atomic_load(&bar[p], __ATOMIC_ACQUIRE, __HIP_MEMORY_SCOPE_AGENT);
    }
    __syncthreads();
}

// ---- prep: cvt X->bf16, W1->W1T bf16, Wmu->WmuT bf16, count degrees ----
__global__ __launch_bounds__(256) void k_prep(const float* __restrict__ X, unsigned short* __restrict__ Xb,
                                              const float* __restrict__ W1, unsigned short* __restrict__ W1T,
                                              const float* __restrict__ Wmu, unsigned short* __restrict__ WmuT,
                                              const int* __restrict__ dst, int* __restrict__ deg) {
    int b = blockIdx.x;
    if (b < 6144) {                       // X: 12288*512/4 float4
        int i = b * 256 + threadIdx.x;
        float4 v = ((const float4*)X)[i];
        ushort4 o;
        o.x = f2bf(v.x); o.y = f2bf(v.y); o.z = f2bf(v.z); o.w = f2bf(v.w);
        ((ushort4*)Xb)[i] = o;
    } else if (b < 6656) {                // W1T: 512*256, i = c*512+k
        int i = (b - 6144) * 256 + threadIdx.x;
        int c = i >> 9, k = i & 511;
        W1T[i] = f2bf(W1[k * DH + c]);
    } else if (b < 6720) {                // WmuT: 64*256, i = c*256+k
        int i = (b - 6656) * 256 + threadIdx.x;
        int c = i >> 8, k = i & 255;
        WmuT[i] = f2bf(Wmu[k * DZ + c]);
    } else {                              // degree count: 1536 blocks
        int e = (b - 6720) * 256 + threadIdx.x;
        atomicAdd(&deg[dst[e]], 1);
    }
}

// ---- FUSED: block 96 scan->flag; blocks 0..95 gemm1 (norm from deg); 96..287 scatter ----
__global__ __launch_bounds__(512) void k_sg(const unsigned short* __restrict__ Xb,
                                            const unsigned short* __restrict__ W1T,
                                            const float* __restrict__ b1, const int* __restrict__ deg,
                                            float* __restrict__ norm, unsigned short* __restrict__ g1,
                                            const int* __restrict__ src, const int* __restrict__ dst,
                                            int* __restrict__ rp, int* __restrict__ cursor,
                                            int* __restrict__ ssrc, int* __restrict__ flag) {
    __shared__ int sp[512];
    if (blockIdx.x < 96) {
        int j = blockIdx.x;
        int wid = threadIdx.x >> 6;
        int lane = threadIdx.x & 63;
        int ln = lane & 15, kg = lane >> 4;
        int rb = (j >> 1) * 256 + (wid >> 1) * 64;
        int cb = (j & 1) * 128 + (wid & 1) * 64;
        f32x4 acc[4][4] = {};
        const unsigned short* xa = Xb + (size_t)(rb + ln) * DIN + kg * 8;
        const unsigned short* wb = W1T + (size_t)(cb + ln) * DIN + kg * 8;
        for (int ks = 0; ks < 16; ++ks) {
            int k0 = ks * 32;
            bf16x8 a[4], b[4];
#pragma unroll
            for (int m = 0; m < 4; ++m) a[m] = *(const bf16x8*)(xa + (size_t)m * 16 * DIN + k0);
#pragma unroll
            for (int n = 0; n < 4; ++n) b[n] = *(const bf16x8*)(wb + (size_t)n * 16 * DIN + k0);
#pragma unroll
            for (int m = 0; m < 4; ++m)
#pragma unroll
                for (int n = 0; n < 4; ++n)
                    acc[m][n] = __builtin_amdgcn_mfma_f32_16x16x32_bf16(a[m], b[n], acc[m][n], 0, 0, 0);
        }
#pragma unroll
        for (int m = 0; m < 4; ++m)
#pragma unroll
            for (int r = 0; r < 4; ++r) {
                int row = rb + m * 16 + kg * 4 + r;
                float ni = rsqrtf((float)deg[row] + 1.0f);
#pragma unroll
                for (int n = 0; n < 4; ++n) {
                    int col = cb + n * 16 + ln;
                    g1[(size_t)row * DH + col] = f2bf(ni * (acc[m][n][r] + b1[col]));
                }
            }
    } else {
        int t = threadIdx.x;
        if (blockIdx.x == 96) {
            int base = t * 24;
            int loc[24];
            int s = 0;
#pragma unroll
            for (int j = 0; j < 24; ++j) {
                int c = deg[base + j];
                norm[base + j] = rsqrtf((float)c + 1.0f);
                cursor[base + j] = 0;
                loc[j] = s; s += c;
            }
            sp[t] = s;
            __syncthreads();
            for (int off = 1; off < 512; off <<= 1) {
                int v = (t >= off) ? sp[t - off] : 0;
                __syncthreads();
                sp[t] += v;
                __syncthreads();
            }
            int pre = (t == 0) ? 0 : sp[t - 1];
#pragma unroll
            for (int j = 0; j < 24; ++j) rp[base + j] = pre + loc[j];
            if (t == 511) rp[N_NODES] = sp[511];
            __threadfence();
            __syncthreads();
            if (t == 0)
                __hip_atomic_store(flag, 1, __ATOMIC_RELEASE, __HIP_MEMORY_SCOPE_AGENT);
        } else {
            if (t == 0) {
                while (__hip_atomic_load(flag, __ATOMIC_RELAXED, __HIP_MEMORY_SCOPE_AGENT) == 0)
                    __builtin_amdgcn_s_sleep(8);
                (void)__hip_atomic_load(flag, __ATOMIC_ACQUIRE, __HIP_MEMORY_SCOPE_AGENT);
            }
            __syncthreads();
        }
        int base = (blockIdx.x - 96) * 512 + t;
#pragma unroll
        for (int e = base; e < N_EDGES; e += 192 * 512) {
            int d = dst[e];
            int pos = atomicAdd(&cursor[d], 1);
            ssrc[rp[d] + pos] = src[e];
        }
    }
}

// ---- FUSED agg1 -> gemm2 -> agg2: one kernel, 2048 blocks (8/CU resident by
//      launch_bounds(256,8) => VGPR<=64), two grid barriers. Phase bodies identical. ----
__global__ __launch_bounds__(256, 8) void k_a12(
    const unsigned short* __restrict__ g1,
    const int* __restrict__ rp, const int* __restrict__ ssrc,
    const float* __restrict__ norm, const float* __restrict__ Wsig,
    const unsigned short* __restrict__ WmuT,
    unsigned short* __restrict__ G2, float* __restrict__ tvec, float* __restrict__ qv,
    unsigned short* __restrict__ Pb,
    const float* __restrict__ bmu, const float* __restrict__ bsig,
    const float* __restrict__ eps,
    float* __restrict__ mus_out, float* __restrict__ logs_out,
    unsigned short* __restrict__ Zb, int* __restrict__ bar) {

    int w = threadIdx.x >> 6;
    int lane = threadIdx.x & 63;
    int gw = blockIdx.x * 4 + w;          // 0..8191

    // ---- Phase A: agg1 (wave-per-node, stride 8192) ----
    {
        int half = lane >> 5, lh = lane & 31;
        size_t cho = (size_t)lh * 8;
        for (int i = gw; i < N_NODES; i += 8192) {
            int beg = rp[i], end = rp[i + 1];
            int itn = (end - beg + 1) >> 1;
            float a8[8] = {};
            float ssum = 0.f;
#pragma unroll 2
            for (int it = 0; it < itn; ++it) {
                int e = beg + it * 2 + half;
                if (e < end) {
                    int s = ssrc[e];
                    u16x8 v = *(const u16x8*)(g1 + ((size_t)s << 8) + cho);
                    ssum += norm[s];
#pragma unroll
                    for (int j = 0; j < 8; ++j) a8[j] += bf2f(v[j]);
                }
            }
            if (half == 0) {
                u16x8 v = *(const u16x8*)(g1 + ((size_t)i << 8) + cho);
#pragma unroll
                for (int j = 0; j < 8; ++j) a8[j] += bf2f(v[j]);
            }
#pragma unroll
            for (int j = 0; j < 8; ++j) a8[j] += __shfl_xor(a8[j], 32);
            ssum += __shfl_xor(ssum, 32);
            float ni = norm[i];
            const float4 ws0 = *(const float4*)(Wsig + cho);
            const float4 ws1 = *(const float4*)(Wsig + cho + 4);
            float g[8];
#pragma unroll
            for (int j = 0; j < 8; ++j) g[j] = ni * fmaxf(ni * a8[j], 0.f);
            float qp = g[0] * ws0.x + g[1] * ws0.y + g[2] * ws0.z + g[3] * ws0.w
                     + g[4] * ws1.x + g[5] * ws1.y + g[6] * ws1.z + g[7] * ws1.w;
            if (half == 0) {
                u16x8 o;
#pragma unroll
                for (int j = 0; j < 8; ++j) o[j] = f2bf(g[j]);
                *(u16x8*)(G2 + ((size_t)i << 8) + cho) = o;
            }
#pragma unroll
            for (int m = 16; m >= 1; m >>= 1) qp += __shfl_xor(qp, m);
            if (lane == 0) {
                tvec[i] = ssum + ni;
                qv[i] = qp;
            }
        }
    }
    gridbar(bar, 0, NBA);

    // ---- Phase B: gemm2 (768 wave-jobs of 16 rows) ----
    if (gw < 768) {
        int ln = lane & 15, kg = lane >> 4;
        int rb = gw * 16;
        f32x4 acc[4] = {};
        const unsigned short* xa = G2 + (size_t)(rb + ln) * DH + kg * 8;
        const unsigned short* wb = WmuT + (size_t)ln * DH + kg * 8;
#pragma unroll
        for (int ks = 0; ks < 8; ++ks) {
            int k0 = ks * 32;
            bf16x8 a = *(const bf16x8*)(xa + k0);
            bf16x8 b[4];
#pragma unroll
            for (int n = 0; n < 4; ++n) b[n] = *(const bf16x8*)(wb + (size_t)n * 16 * DH + k0);
#pragma unroll
            for (int n = 0; n < 4; ++n)
                acc[n] = __builtin_amdgcn_mfma_f32_16x16x32_bf16(a, b[n], acc[n], 0, 0, 0);
        }
#pragma unroll
        for (int n = 0; n < 4; ++n)
#pragma unroll
            for (int r = 0; r < 4; ++r)
                Pb[(size_t)(rb + kg * 4 + r) * DZ + n * 16 + ln] = f2bf(acc[n][r]);
    }
    gridbar(bar, 1, NBA);

    // ---- Phase C: agg2 (wave-per-node, stride 8192) ----
    {
        int grp = lane >> 4, li = lane & 15;
        int co = li * 4;
        for (int i = gw; i < N_NODES; i += 8192) {
            int beg = rp[i], end = rp[i + 1];
            int itn = (end - beg + 3) >> 2;
            float a4[4] = {};
            float qa = 0.f;
#pragma unroll 2
            for (int it = 0; it < itn; ++it) {
                int e = beg + it * 4 + grp;
                if (e < end) {
                    int s = ssrc[e];
                    ushort4 v = *(const ushort4*)(Pb + ((size_t)s << 6) + co);
                    qa += qv[s];
                    a4[0] += bf2f(v.x); a4[1] += bf2f(v.y); a4[2] += bf2f(v.z); a4[3] += bf2f(v.w);
                }
            }
            if (grp == 0) {
                ushort4 v = *(const ushort4*)(Pb + ((size_t)i << 6) + co);
                qa += qv[i];
                a4[0] += bf2f(v.x); a4[1] += bf2f(v.y); a4[2] += bf2f(v.z); a4[3] += bf2f(v.w);
            }
#pragma unroll
            for (int j = 0; j < 4; ++j) {
                a4[j] += __shfl_xor(a4[j], 16);
                a4[j] += __shfl_xor(a4[j], 32);
            }
            qa += __shfl_xor(qa, 16);
            qa += __shfl_xor(qa, 32);
            float ni = norm[i], tv = tvec[i];
            float ls = ni * (qa + bsig[0] * tv);
            float sig = expf(0.5f * ls);
            if (lane == 0) logs_out[i] = ls;
            if (lane < 16) {
                const float4 bm = *(const float4*)(bmu + co);
                float4 mu;
                mu.x = ni * (a4[0] + bm.x * tv);
                mu.y = ni * (a4[1] + bm.y * tv);
                mu.z = ni * (a4[2] + bm.z * tv);
                mu.w = ni * (a4[3] + bm.w * tv);
                size_t oidx = ((size_t)i << 6) + co;
                *(float4*)(mus_out + oidx) = mu;
                const float4 ep = *(const float4*)(eps + oidx);
                ushort4 z;
                z.x = f2bf(mu.x + sig * ep.x);
                z.y = f2bf(mu.y + sig * ep.y);
                z.z = f2bf(mu.z + sig * ep.z);
                z.w = f2bf(mu.w + sig * ep.w);
                *(ushort4*)(Zb + oidx) = z;
            }
        }
    }
}

// ---- ZZt = Z @ Z^T. 64x256 tile, 2-phase LDS epilogue, NT stores. ----
#define LPAD 260
__global__ __launch_bounds__(256) void k_zzt(const unsigned short* __restrict__ Zb, float* __restrict__ out) {
    __shared__ float lds[32 * LPAD];
    int w = threadIdx.x >> 6;
    int lane = threadIdx.x & 63;
    int ln = lane & 15, kg = lane >> 4;
    int rb = blockIdx.x * 64;           // output rows
    int cb = blockIdx.y * 256 + w * 64; // output cols, wave-split
    bf16x8 a[4][2], b[4][2];
#pragma unroll
    for (int m = 0; m < 4; ++m)
#pragma unroll
        for (int kc = 0; kc < 2; ++kc)
            a[m][kc] = *(const bf16x8*)(Zb + (size_t)(rb + m * 16 + ln) * DZ + kc * 32 + kg * 8);
#pragma unroll
    for (int n = 0; n < 4; ++n)
#pragma unroll
        for (int kc = 0; kc < 2; ++kc)
            b[n][kc] = *(const bf16x8*)(Zb + (size_t)(cb + n * 16 + ln) * DZ + kc * 32 + kg * 8);
    f32x4 acc[4][4] = {};
#pragma unroll
    for (int m = 0; m < 4; ++m)
#pragma unroll
        for (int n = 0; n < 4; ++n) {
            acc[m][n] = __builtin_amdgcn_mfma_f32_16x16x32_bf16(a[m][0], b[n][0], acc[m][n], 0, 0, 0);
            acc[m][n] = __builtin_amdgcn_mfma_f32_16x16x32_bf16(a[m][1], b[n][1], acc[m][n], 0, 0, 0);
        }
    int c4 = (threadIdx.x & 63) * 4;
    int rw = threadIdx.x >> 6;
    size_t colbase = (size_t)blockIdx.y * 256 + c4;
#pragma unroll
    for (int p = 0; p < 2; ++p) {
        if (p) __syncthreads();
#pragma unroll
        for (int mm = 0; mm < 2; ++mm) {
            int m = p * 2 + mm;
#pragma unroll
            for (int n = 0; n < 4; ++n)
#pragma unroll
                for (int r = 0; r < 4; ++r)
                    lds[(mm * 16 + kg * 4 + r) * LPAD + w * 64 + n * 16 + ln] = acc[m][n][r];
        }
        __syncthreads();
#pragma unroll
        for (int it = 0; it < 8; ++it) {
            int rl = it * 4 + rw;
            f32x4 v = *(const f32x4*)&lds[rl * LPAD + c4];
            __builtin_nontemporal_store(v, (f32x4*)(out + (size_t)(rb + p * 32 + rl) * N_NODES + colbase));
        }
    }
}

extern "C" void kernel_launch(void* const* d_in, const int* in_sizes, int n_in,
                              void* d_out, int out_size, void* d_ws, size_t ws_size,
                              hipStream_t stream) {
    const float* X = (const float*)d_in[0];
    const int* edge = (const int*)d_in[1];
    const float* W1 = (const float*)d_in[2];
    const float* b1 = (const float*)d_in[3];
    const float* Wmu = (const float*)d_in[4];
    const float* bmu = (const float*)d_in[5];
    const float* Wsig = (const float*)d_in[6];
    const float* bsig = (const float*)d_in[7];
    const float* eps = (const float*)d_in[8];

    const int* esrc = edge;
    const int* edst = edge + N_EDGES;

    char* w = (char*)d_ws;
    int* flag = (int*)w;                                          // [0]=scan flag, [1..2]=bar
    int* bar = (int*)w + 1;        w += 64;
    int* deg = (int*)w;            w += (size_t)N_NODES * 4;
    int* cursor = (int*)w;         w += (size_t)N_NODES * 4;
    float* norm = (float*)w;       w += (size_t)N_NODES * 4;
    float* tvec = (float*)w;       w += (size_t)N_NODES * 4;
    float* qv = (float*)w;         w += (size_t)N_NODES * 4;
    int* rowptr = (int*)w;         w += (size_t)(N_NODES + 64) * 4;
    int* ssrc = (int*)w;           w += (size_t)N_EDGES * 4;
    unsigned short* Xb = (unsigned short*)w;   w += (size_t)N_NODES * DIN * 2;
    unsigned short* W1T = (unsigned short*)w;  w += (size_t)DIN * DH * 2;
    unsigned short* WmuT = (unsigned short*)w; w += (size_t)DH * DZ * 2;
    unsigned short* g1 = (unsigned short*)w;   w += (size_t)N_NODES * DH * 2;
    unsigned short* G2 = (unsigned short*)w;   w += (size_t)N_NODES * DH * 2;
    unsigned short* Pb = (unsigned short*)w;   w += (size_t)N_NODES * DZ * 2;
    unsigned short* Zb = (unsigned short*)w;   w += (size_t)N_NODES * DZ * 2;

    float* out_zzt = (float*)d_out;
    float* out_mus = out_zzt + (size_t)N_NODES * N_NODES;
    float* out_logs = out_mus + (size_t)N_NODES * DZ;

    (void)hipMemsetAsync(d_ws, 0, 64 + (size_t)N_NODES * 4, stream);   // flag+bar+deg
    k_prep<<<8256, 256, 0, stream>>>(X, Xb, W1, W1T, Wmu, WmuT, edst, deg);
    k_sg<<<288, 512, 0, stream>>>(Xb, W1T, b1, deg, norm, g1, esrc, edst, rowptr, cursor, ssrc, flag);
    k_a12<<<NBA, 256, 0, stream>>>(g1, rowptr, ssrc, norm, Wsig, WmuT, G2, tvec, qv, Pb,
                                   bmu, bsig, eps, out_mus, out_logs, Zb, bar);
    k_zzt<<<dim3(N_NODES / 64, N_NODES / 256), 256, 0, stream>>>(Zb, out_zzt);
}

// Round 16
// 256.585 us; speedup vs baseline: 2.6491x; 2.6491x over previous
//
#include <hip/hip_runtime.h>

#define N_NODES 12288
#define N_EDGES 393216
#define DIN 512
#define DH 256
#define DZ 64

typedef __bf16 bf16x8 __attribute__((ext_vector_type(8)));
typedef float f32x4 __attribute__((ext_vector_type(4)));
typedef unsigned short u16x8 __attribute__((ext_vector_type(8)));

static __device__ __forceinline__ unsigned short f2bf(float f) {
    unsigned int u = __float_as_uint(f);
    unsigned int r = (u + 0x7fffu + ((u >> 16) & 1u)) >> 16;
    return (unsigned short)r;
}
static __device__ __forceinline__ float bf2f(unsigned short u) {
    return __uint_as_float((unsigned int)u << 16);
}

// ---- prep: cvt X->bf16, W1->W1T bf16, Wmu->WmuT bf16, count degrees ----
__global__ __launch_bounds__(256) void k_prep(const float* __restrict__ X, unsigned short* __restrict__ Xb,
                                              const float* __restrict__ W1, unsigned short* __restrict__ W1T,
                                              const float* __restrict__ Wmu, unsigned short* __restrict__ WmuT,
                                              const int* __restrict__ dst, int* __restrict__ deg) {
    int b = blockIdx.x;
    if (b < 6144) {                       // X: 12288*512/4 float4
        int i = b * 256 + threadIdx.x;
        float4 v = ((const float4*)X)[i];
        ushort4 o;
        o.x = f2bf(v.x); o.y = f2bf(v.y); o.z = f2bf(v.z); o.w = f2bf(v.w);
        ((ushort4*)Xb)[i] = o;
    } else if (b < 6656) {                // W1T: 512*256, i = c*512+k
        int i = (b - 6144) * 256 + threadIdx.x;
        int c = i >> 9, k = i & 511;
        W1T[i] = f2bf(W1[k * DH + c]);
    } else if (b < 6720) {                // WmuT: 64*256, i = c*256+k
        int i = (b - 6656) * 256 + threadIdx.x;
        int c = i >> 8, k = i & 255;
        WmuT[i] = f2bf(Wmu[k * DZ + c]);
    } else {                              // degree count: 1536 blocks
        int e = (b - 6720) * 256 + threadIdx.x;
        atomicAdd(&deg[dst[e]], 1);
    }
}

// ---- FUSED: block 96 scan->flag; blocks 0..95 gemm1 (norm from deg);
//      blocks 96..767 scatter after flag (widened: <=2 edges/thread) ----
__global__ __launch_bounds__(512) void k_sg(const unsigned short* __restrict__ Xb,
                                            const unsigned short* __restrict__ W1T,
                                            const float* __restrict__ b1, const int* __restrict__ deg,
                                            float* __restrict__ norm, unsigned short* __restrict__ g1,
                                            const int* __restrict__ src, const int* __restrict__ dst,
                                            int* __restrict__ rp, int* __restrict__ cursor,
                                            int* __restrict__ ssrc, int* __restrict__ flag) {
    __shared__ int sp[512];
    if (blockIdx.x < 96) {
        // ---- gemm1: g1 = rsqrt(deg+1) .* (X @ W1 + b1) ----
        int j = blockIdx.x;
        int wid = threadIdx.x >> 6;
        int lane = threadIdx.x & 63;
        int ln = lane & 15, kg = lane >> 4;
        int rb = (j >> 1) * 256 + (wid >> 1) * 64;
        int cb = (j & 1) * 128 + (wid & 1) * 64;
        f32x4 acc[4][4] = {};
        const unsigned short* xa = Xb + (size_t)(rb + ln) * DIN + kg * 8;
        const unsigned short* wb = W1T + (size_t)(cb + ln) * DIN + kg * 8;
        for (int ks = 0; ks < 16; ++ks) {
            int k0 = ks * 32;
            bf16x8 a[4], b[4];
#pragma unroll
            for (int m = 0; m < 4; ++m) a[m] = *(const bf16x8*)(xa + (size_t)m * 16 * DIN + k0);
#pragma unroll
            for (int n = 0; n < 4; ++n) b[n] = *(const bf16x8*)(wb + (size_t)n * 16 * DIN + k0);
#pragma unroll
            for (int m = 0; m < 4; ++m)
#pragma unroll
                for (int n = 0; n < 4; ++n)
                    acc[m][n] = __builtin_amdgcn_mfma_f32_16x16x32_bf16(a[m], b[n], acc[m][n], 0, 0, 0);
        }
#pragma unroll
        for (int m = 0; m < 4; ++m)
#pragma unroll
            for (int r = 0; r < 4; ++r) {
                int row = rb + m * 16 + kg * 4 + r;
                float ni = rsqrtf((float)deg[row] + 1.0f);   // == norm[row], no scan dep
#pragma unroll
                for (int n = 0; n < 4; ++n) {
                    int col = cb + n * 16 + ln;
                    g1[(size_t)row * DH + col] = f2bf(ni * (acc[m][n][r] + b1[col]));
                }
            }
    } else {
        int t = threadIdx.x;
        if (blockIdx.x == 96) {
            // ---- scan: rowptr prefix + norm + cursor-zero, then release flag ----
            int base = t * 24;
            int loc[24];
            int s = 0;
#pragma unroll
            for (int j = 0; j < 24; ++j) {
                int c = deg[base + j];
                norm[base + j] = rsqrtf((float)c + 1.0f);
                cursor[base + j] = 0;
                loc[j] = s; s += c;
            }
            sp[t] = s;
            __syncthreads();
            for (int off = 1; off < 512; off <<= 1) {
                int v = (t >= off) ? sp[t - off] : 0;
                __syncthreads();
                sp[t] += v;
                __syncthreads();
            }
            int pre = (t == 0) ? 0 : sp[t - 1];
#pragma unroll
            for (int j = 0; j < 24; ++j) rp[base + j] = pre + loc[j];
            if (t == 511) rp[N_NODES] = sp[511];
            __threadfence();
            __syncthreads();
            if (t == 0)
                __hip_atomic_store(flag, 1, __ATOMIC_RELEASE, __HIP_MEMORY_SCOPE_AGENT);
        } else {
            // ---- wait for scan (relaxed spin, single acquire) ----
            if (t == 0) {
                while (__hip_atomic_load(flag, __ATOMIC_RELAXED, __HIP_MEMORY_SCOPE_AGENT) == 0)
                    __builtin_amdgcn_s_sleep(8);
                (void)__hip_atomic_load(flag, __ATOMIC_ACQUIRE, __HIP_MEMORY_SCOPE_AGENT);
            }
            __syncthreads();
        }
        // ---- scatter (blocks 96..767): 672 blocks x 512 thr, <=2 edges/thread ----
        int base = (blockIdx.x - 96) * 512 + t;
        for (int e = base; e < N_EDGES; e += 672 * 512) {
            int d = dst[e];
            int pos = atomicAdd(&cursor[d], 1);
            ssrc[rp[d] + pos] = src[e];
        }
    }
}

// ---- agg1: wave-per-node, 2 edges/instruction (half-wave x ushort8). ----
__global__ __launch_bounds__(256) void k_agg1(const unsigned short* __restrict__ g1,
                                              const int* __restrict__ rp, const int* __restrict__ ssrc,
                                              const float* __restrict__ norm, const float* __restrict__ Wsig,
                                              unsigned short* __restrict__ G2, float* __restrict__ tvec,
                                              float* __restrict__ qv) {
    int w = threadIdx.x >> 6;
    int lane = threadIdx.x & 63;
    int half = lane >> 5, lh = lane & 31;
    int i = blockIdx.x * 4 + w;
    int beg = rp[i], end = rp[i + 1];
    int itn = (end - beg + 1) >> 1;
    size_t cho = (size_t)lh * 8;
    float a8[8] = {};
    float ssum = 0.f;
#pragma unroll 2
    for (int it = 0; it < itn; ++it) {
        int e = beg + it * 2 + half;
        if (e < end) {
            int s = ssrc[e];
            u16x8 v = *(const u16x8*)(g1 + ((size_t)s << 8) + cho);
            ssum += norm[s];
#pragma unroll
            for (int j = 0; j < 8; ++j) a8[j] += bf2f(v[j]);
        }
    }
    if (half == 0) {   // self-loop once
        u16x8 v = *(const u16x8*)(g1 + ((size_t)i << 8) + cho);
#pragma unroll
        for (int j = 0; j < 8; ++j) a8[j] += bf2f(v[j]);
    }
#pragma unroll
    for (int j = 0; j < 8; ++j) a8[j] += __shfl_xor(a8[j], 32);
    ssum += __shfl_xor(ssum, 32);
    float ni = norm[i];
    const float4 ws0 = *(const float4*)(Wsig + cho);
    const float4 ws1 = *(const float4*)(Wsig + cho + 4);
    float g[8];
#pragma unroll
    for (int j = 0; j < 8; ++j) g[j] = ni * fmaxf(ni * a8[j], 0.f);
    float qp = g[0] * ws0.x + g[1] * ws0.y + g[2] * ws0.z + g[3] * ws0.w
             + g[4] * ws1.x + g[5] * ws1.y + g[6] * ws1.z + g[7] * ws1.w;
    if (half == 0) {
        u16x8 o;
#pragma unroll
        for (int j = 0; j < 8; ++j) o[j] = f2bf(g[j]);
        *(u16x8*)(G2 + ((size_t)i << 8) + cho) = o;
    }
#pragma unroll
    for (int m = 16; m >= 1; m >>= 1) qp += __shfl_xor(qp, m);
    if (lane == 0) {
        tvec[i] = ssum + ni;
        qv[i] = qp;
    }
}

// ---- gemm2: P = G2 @ Wmu (bf16 MFMA, bf16 out), M=12288 K=256 N=64 ----
__global__ __launch_bounds__(256) void k_gemm2(const unsigned short* __restrict__ G2,
                                               const unsigned short* __restrict__ WmuT,
                                               unsigned short* __restrict__ Pb) {
    int wid = threadIdx.x >> 6;
    int lane = threadIdx.x & 63;
    int ln = lane & 15, kg = lane >> 4;
    int rb = blockIdx.x * 128 + wid * 32;
    f32x4 acc[2][4] = {};
    const unsigned short* xa = G2 + (size_t)(rb + ln) * DH + kg * 8;
    const unsigned short* wb = WmuT + (size_t)ln * DH + kg * 8;
    for (int ks = 0; ks < 8; ++ks) {
        int k0 = ks * 32;
        bf16x8 a[2], b[4];
#pragma unroll
        for (int m = 0; m < 2; ++m) a[m] = *(const bf16x8*)(xa + (size_t)m * 16 * DH + k0);
#pragma unroll
        for (int n = 0; n < 4; ++n) b[n] = *(const bf16x8*)(wb + (size_t)n * 16 * DH + k0);
#pragma unroll
        for (int m = 0; m < 2; ++m)
#pragma unroll
            for (int n = 0; n < 4; ++n)
                acc[m][n] = __builtin_amdgcn_mfma_f32_16x16x32_bf16(a[m], b[n], acc[m][n], 0, 0, 0);
    }
#pragma unroll
    for (int m = 0; m < 2; ++m)
#pragma unroll
        for (int n = 0; n < 4; ++n)
#pragma unroll
            for (int r = 0; r < 4; ++r) {
                int row = rb + m * 16 + kg * 4 + r;
                int col = n * 16 + ln;
                Pb[(size_t)row * DZ + col] = f2bf(acc[m][n][r]);
            }
}

// ---- agg2: wave-per-node, 4 edges/iteration (16-lane groups x ushort4). ----
__global__ __launch_bounds__(256) void k_agg2(const unsigned short* __restrict__ Pb,
                                              const float* __restrict__ qv,
                                              const int* __restrict__ rp, const int* __restrict__ ssrc,
                                              const float* __restrict__ norm, const float* __restrict__ tvec,
                                              const float* __restrict__ bmu, const float* __restrict__ bsig,
                                              const float* __restrict__ eps,
                                              float* __restrict__ mus_out, float* __restrict__ logs_out,
                                              unsigned short* __restrict__ Zb) {
    int w = threadIdx.x >> 6;
    int lane = threadIdx.x & 63;
    int grp = lane >> 4, li = lane & 15;
    int i = blockIdx.x * 4 + w;
    int beg = rp[i], end = rp[i + 1];
    int itn = (end - beg + 3) >> 2;
    int co = li * 4;
    float a4[4] = {};
    float qa = 0.f;
#pragma unroll 2
    for (int it = 0; it < itn; ++it) {
        int e = beg + it * 4 + grp;
        if (e < end) {
            int s = ssrc[e];
            ushort4 v = *(const ushort4*)(Pb + ((size_t)s << 6) + co);
            qa += qv[s];
            a4[0] += bf2f(v.x); a4[1] += bf2f(v.y); a4[2] += bf2f(v.z); a4[3] += bf2f(v.w);
        }
    }
    if (grp == 0) {   // self-loop
        ushort4 v = *(const ushort4*)(Pb + ((size_t)i << 6) + co);
        qa += qv[i];
        a4[0] += bf2f(v.x); a4[1] += bf2f(v.y); a4[2] += bf2f(v.z); a4[3] += bf2f(v.w);
    }
#pragma unroll
    for (int j = 0; j < 4; ++j) {
        a4[j] += __shfl_xor(a4[j], 16);
        a4[j] += __shfl_xor(a4[j], 32);
    }
    qa += __shfl_xor(qa, 16);
    qa += __shfl_xor(qa, 32);
    float ni = norm[i], tv = tvec[i];
    float ls = ni * (qa + bsig[0] * tv);
    float sig = expf(0.5f * ls);
    if (lane == 0) logs_out[i] = ls;
    if (lane < 16) {
        const float4 bm = *(const float4*)(bmu + co);
        float4 mu;
        mu.x = ni * (a4[0] + bm.x * tv);
        mu.y = ni * (a4[1] + bm.y * tv);
        mu.z = ni * (a4[2] + bm.z * tv);
        mu.w = ni * (a4[3] + bm.w * tv);
        size_t oidx = ((size_t)i << 6) + co;
        *(float4*)(mus_out + oidx) = mu;
        const float4 ep = *(const float4*)(eps + oidx);
        ushort4 z;
        z.x = f2bf(mu.x + sig * ep.x);
        z.y = f2bf(mu.y + sig * ep.y);
        z.z = f2bf(mu.z + sig * ep.z);
        z.w = f2bf(mu.w + sig * ep.w);
        *(ushort4*)(Zb + oidx) = z;
    }
}

// ---- ZZt = Z @ Z^T. 64x256 tile, 2-phase LDS epilogue, NT stores. ----
#define LPAD 260
__global__ __launch_bounds__(256) void k_zzt(const unsigned short* __restrict__ Zb, float* __restrict__ out) {
    __shared__ float lds[32 * LPAD];
    int w = threadIdx.x >> 6;
    int lane = threadIdx.x & 63;
    int ln = lane & 15, kg = lane >> 4;
    int rb = blockIdx.x * 64;           // output rows
    int cb = blockIdx.y * 256 + w * 64; // output cols, wave-split
    bf16x8 a[4][2], b[4][2];
#pragma unroll
    for (int m = 0; m < 4; ++m)
#pragma unroll
        for (int kc = 0; kc < 2; ++kc)
            a[m][kc] = *(const bf16x8*)(Zb + (size_t)(rb + m * 16 + ln) * DZ + kc * 32 + kg * 8);
#pragma unroll
    for (int n = 0; n < 4; ++n)
#pragma unroll
        for (int kc = 0; kc < 2; ++kc)
            b[n][kc] = *(const bf16x8*)(Zb + (size_t)(cb + n * 16 + ln) * DZ + kc * 32 + kg * 8);
    f32x4 acc[4][4] = {};
#pragma unroll
    for (int m = 0; m < 4; ++m)
#pragma unroll
        for (int n = 0; n < 4; ++n) {
            acc[m][n] = __builtin_amdgcn_mfma_f32_16x16x32_bf16(a[m][0], b[n][0], acc[m][n], 0, 0, 0);
            acc[m][n] = __builtin_amdgcn_mfma_f32_16x16x32_bf16(a[m][1], b[n][1], acc[m][n], 0, 0, 0);
        }
    int c4 = (threadIdx.x & 63) * 4;
    int rw = threadIdx.x >> 6;
    size_t colbase = (size_t)blockIdx.y * 256 + c4;
#pragma unroll
    for (int p = 0; p < 2; ++p) {
        if (p) __syncthreads();
#pragma unroll
        for (int mm = 0; mm < 2; ++mm) {
            int m = p * 2 + mm;
#pragma unroll
            for (int n = 0; n < 4; ++n)
#pragma unroll
                for (int r = 0; r < 4; ++r)
                    lds[(mm * 16 + kg * 4 + r) * LPAD + w * 64 + n * 16 + ln] = acc[m][n][r];
        }
        __syncthreads();
#pragma unroll
        for (int it = 0; it < 8; ++it) {
            int rl = it * 4 + rw;
            f32x4 v = *(const f32x4*)&lds[rl * LPAD + c4];
            __builtin_nontemporal_store(v, (f32x4*)(out + (size_t)(rb + p * 32 + rl) * N_NODES + colbase));
        }
    }
}

extern "C" void kernel_launch(void* const* d_in, const int* in_sizes, int n_in,
                              void* d_out, int out_size, void* d_ws, size_t ws_size,
                              hipStream_t stream) {
    const float* X = (const float*)d_in[0];
    const int* edge = (const int*)d_in[1];
    const float* W1 = (const float*)d_in[2];
    const float* b1 = (const float*)d_in[3];
    const float* Wmu = (const float*)d_in[4];
    const float* bmu = (const float*)d_in[5];
    const float* Wsig = (const float*)d_in[6];
    const float* bsig = (const float*)d_in[7];
    const float* eps = (const float*)d_in[8];

    const int* esrc = edge;
    const int* edst = edge + N_EDGES;

    char* w = (char*)d_ws;
    int* flag = (int*)w;           w += 64;                      // scan-done flag (memset to 0)
    int* deg = (int*)w;            w += (size_t)N_NODES * 4;     // (memset to 0)
    int* cursor = (int*)w;         w += (size_t)N_NODES * 4;
    float* norm = (float*)w;       w += (size_t)N_NODES * 4;
    float* tvec = (float*)w;       w += (size_t)N_NODES * 4;
    float* qv = (float*)w;         w += (size_t)N_NODES * 4;
    int* rowptr = (int*)w;         w += (size_t)(N_NODES + 64) * 4;
    int* ssrc = (int*)w;           w += (size_t)N_EDGES * 4;
    unsigned short* Xb = (unsigned short*)w;   w += (size_t)N_NODES * DIN * 2;
    unsigned short* W1T = (unsigned short*)w;  w += (size_t)DIN * DH * 2;
    unsigned short* WmuT = (unsigned short*)w; w += (size_t)DH * DZ * 2;
    unsigned short* g1 = (unsigned short*)w;   w += (size_t)N_NODES * DH * 2;
    unsigned short* G2 = (unsigned short*)w;   w += (size_t)N_NODES * DH * 2;
    unsigned short* Pb = (unsigned short*)w;   w += (size_t)N_NODES * DZ * 2;
    unsigned short* Zb = (unsigned short*)w;   w += (size_t)N_NODES * DZ * 2;

    float* out_zzt = (float*)d_out;
    float* out_mus = out_zzt + (size_t)N_NODES * N_NODES;
    float* out_logs = out_mus + (size_t)N_NODES * DZ;

    (void)hipMemsetAsync(d_ws, 0, 64 + (size_t)N_NODES * 4, stream);   // flag + deg
    k_prep<<<8256, 256, 0, stream>>>(X, Xb, W1, W1T, Wmu, WmuT, edst, deg);
    k_sg<<<768, 512, 0, stream>>>(Xb, W1T, b1, deg, norm, g1, esrc, edst, rowptr, cursor, ssrc, flag);
    k_agg1<<<N_NODES / 4, 256, 0, stream>>>(g1, rowptr, ssrc, norm, Wsig, G2, tvec, qv);
    k_gemm2<<<N_NODES / 128, 256, 0, stream>>>(G2, WmuT, Pb);
    k_agg2<<<N_NODES / 4, 256, 0, stream>>>(Pb, qv, rowptr, ssrc, norm, tvec, bmu, bsig, eps,
                                            out_mus, out_logs, Zb);
    k_zzt<<<dim3(N_NODES / 64, N_NODES / 256), 256, 0, stream>>>(Zb, out_zzt);
}

// Round 17
// 227.467 us; speedup vs baseline: 2.9882x; 1.1280x over previous
//
#include <hip/hip_runtime.h>

#define N_NODES 12288
#define N_EDGES 393216
#define DIN 512
#define DH 256
#define DZ 64

typedef __bf16 bf16x8 __attribute__((ext_vector_type(8)));
typedef float f32x4 __attribute__((ext_vector_type(4)));
typedef unsigned short u16x8 __attribute__((ext_vector_type(8)));

static __device__ __forceinline__ unsigned short f2bf(float f) {
    unsigned int u = __float_as_uint(f);
    unsigned int r = (u + 0x7fffu + ((u >> 16) & 1u)) >> 16;
    return (unsigned short)r;
}
static __device__ __forceinline__ float bf2f(unsigned short u) {
    return __uint_as_float((unsigned int)u << 16);
}

// ---- prep: cvt X->bf16, W1->W1T bf16, Wmu->WmuT bf16, count degrees ----
__global__ __launch_bounds__(256) void k_prep(const float* __restrict__ X, unsigned short* __restrict__ Xb,
                                              const float* __restrict__ W1, unsigned short* __restrict__ W1T,
                                              const float* __restrict__ Wmu, unsigned short* __restrict__ WmuT,
                                              const int* __restrict__ dst, int* __restrict__ deg) {
    int b = blockIdx.x;
    if (b < 6144) {                       // X: 12288*512/4 float4
        int i = b * 256 + threadIdx.x;
        float4 v = ((const float4*)X)[i];
        ushort4 o;
        o.x = f2bf(v.x); o.y = f2bf(v.y); o.z = f2bf(v.z); o.w = f2bf(v.w);
        ((ushort4*)Xb)[i] = o;
    } else if (b < 6656) {                // W1T: 512*256, i = c*512+k
        int i = (b - 6144) * 256 + threadIdx.x;
        int c = i >> 9, k = i & 511;
        W1T[i] = f2bf(W1[k * DH + c]);
    } else if (b < 6720) {                // WmuT: 64*256, i = c*256+k
        int i = (b - 6656) * 256 + threadIdx.x;
        int c = i >> 8, k = i & 255;
        WmuT[i] = f2bf(Wmu[k * DZ + c]);
    } else {                              // degree count: 1536 blocks
        int e = (b - 6720) * 256 + threadIdx.x;
        atomicAdd(&deg[dst[e]], 1);
    }
}

// ---- FUSED: block 96 scan->flag; blocks 0..95 gemm1 (norm from deg);
//      blocks 96..767 scatter after flag (<=2 edges/thread) ----
__global__ __launch_bounds__(512) void k_sg(const unsigned short* __restrict__ Xb,
                                            const unsigned short* __restrict__ W1T,
                                            const float* __restrict__ b1, const int* __restrict__ deg,
                                            float* __restrict__ norm, unsigned short* __restrict__ g1,
                                            const int* __restrict__ src, const int* __restrict__ dst,
                                            int* __restrict__ rp, int* __restrict__ cursor,
                                            int* __restrict__ ssrc, int* __restrict__ flag) {
    __shared__ int sp[512];
    if (blockIdx.x < 96) {
        // ---- gemm1: g1 = rsqrt(deg+1) .* (X @ W1 + b1) ----
        int j = blockIdx.x;
        int wid = threadIdx.x >> 6;
        int lane = threadIdx.x & 63;
        int ln = lane & 15, kg = lane >> 4;
        int rb = (j >> 1) * 256 + (wid >> 1) * 64;
        int cb = (j & 1) * 128 + (wid & 1) * 64;
        f32x4 acc[4][4] = {};
        const unsigned short* xa = Xb + (size_t)(rb + ln) * DIN + kg * 8;
        const unsigned short* wb = W1T + (size_t)(cb + ln) * DIN + kg * 8;
        for (int ks = 0; ks < 16; ++ks) {
            int k0 = ks * 32;
            bf16x8 a[4], b[4];
#pragma unroll
            for (int m = 0; m < 4; ++m) a[m] = *(const bf16x8*)(xa + (size_t)m * 16 * DIN + k0);
#pragma unroll
            for (int n = 0; n < 4; ++n) b[n] = *(const bf16x8*)(wb + (size_t)n * 16 * DIN + k0);
#pragma unroll
            for (int m = 0; m < 4; ++m)
#pragma unroll
                for (int n = 0; n < 4; ++n)
                    acc[m][n] = __builtin_amdgcn_mfma_f32_16x16x32_bf16(a[m], b[n], acc[m][n], 0, 0, 0);
        }
#pragma unroll
        for (int m = 0; m < 4; ++m)
#pragma unroll
            for (int r = 0; r < 4; ++r) {
                int row = rb + m * 16 + kg * 4 + r;
                float ni = rsqrtf((float)deg[row] + 1.0f);   // == norm[row], no scan dep
#pragma unroll
                for (int n = 0; n < 4; ++n) {
                    int col = cb + n * 16 + ln;
                    g1[(size_t)row * DH + col] = f2bf(ni * (acc[m][n][r] + b1[col]));
                }
            }
    } else {
        int t = threadIdx.x;
        if (blockIdx.x == 96) {
            // ---- scan: rowptr prefix + norm + cursor-zero, then release flag ----
            int base = t * 24;
            int loc[24];
            int s = 0;
#pragma unroll
            for (int j = 0; j < 24; ++j) {
                int c = deg[base + j];
                norm[base + j] = rsqrtf((float)c + 1.0f);
                cursor[base + j] = 0;
                loc[j] = s; s += c;
            }
            sp[t] = s;
            __syncthreads();
            for (int off = 1; off < 512; off <<= 1) {
                int v = (t >= off) ? sp[t - off] : 0;
                __syncthreads();
                sp[t] += v;
                __syncthreads();
            }
            int pre = (t == 0) ? 0 : sp[t - 1];
#pragma unroll
            for (int j = 0; j < 24; ++j) rp[base + j] = pre + loc[j];
            if (t == 511) rp[N_NODES] = sp[511];
            __threadfence();
            __syncthreads();
            if (t == 0)
                __hip_atomic_store(flag, 1, __ATOMIC_RELEASE, __HIP_MEMORY_SCOPE_AGENT);
        } else {
            // ---- wait for scan (relaxed spin, single acquire) ----
            if (t == 0) {
                while (__hip_atomic_load(flag, __ATOMIC_RELAXED, __HIP_MEMORY_SCOPE_AGENT) == 0)
                    __builtin_amdgcn_s_sleep(8);
                (void)__hip_atomic_load(flag, __ATOMIC_ACQUIRE, __HIP_MEMORY_SCOPE_AGENT);
            }
            __syncthreads();
        }
        // ---- scatter (blocks 96..767): 672 blocks x 512 thr, <=2 edges/thread ----
        int base = (blockIdx.x - 96) * 512 + t;
        for (int e = base; e < N_EDGES; e += 672 * 512) {
            int d = dst[e];
            int pos = atomicAdd(&cursor[d], 1);
            ssrc[rp[d] + pos] = src[e];
        }
    }
}

// ---- agg1: wave-per-node, 2 edges/instruction (half-wave x ushort8). ----
__global__ __launch_bounds__(256) void k_agg1(const unsigned short* __restrict__ g1,
                                              const int* __restrict__ rp, const int* __restrict__ ssrc,
                                              const float* __restrict__ norm, const float* __restrict__ Wsig,
                                              unsigned short* __restrict__ G2, float* __restrict__ tvec,
                                              float* __restrict__ qv) {
    int w = threadIdx.x >> 6;
    int lane = threadIdx.x & 63;
    int half = lane >> 5, lh = lane & 31;
    int i = blockIdx.x * 4 + w;
    int beg = rp[i], end = rp[i + 1];
    int itn = (end - beg + 1) >> 1;
    size_t cho = (size_t)lh * 8;
    float a8[8] = {};
    float ssum = 0.f;
#pragma unroll 2
    for (int it = 0; it < itn; ++it) {
        int e = beg + it * 2 + half;
        if (e < end) {
            int s = ssrc[e];
            u16x8 v = *(const u16x8*)(g1 + ((size_t)s << 8) + cho);
            ssum += norm[s];
#pragma unroll
            for (int j = 0; j < 8; ++j) a8[j] += bf2f(v[j]);
        }
    }
    if (half == 0) {   // self-loop once
        u16x8 v = *(const u16x8*)(g1 + ((size_t)i << 8) + cho);
#pragma unroll
        for (int j = 0; j < 8; ++j) a8[j] += bf2f(v[j]);
    }
#pragma unroll
    for (int j = 0; j < 8; ++j) a8[j] += __shfl_xor(a8[j], 32);
    ssum += __shfl_xor(ssum, 32);
    float ni = norm[i];
    const float4 ws0 = *(const float4*)(Wsig + cho);
    const float4 ws1 = *(const float4*)(Wsig + cho + 4);
    float g[8];
#pragma unroll
    for (int j = 0; j < 8; ++j) g[j] = ni * fmaxf(ni * a8[j], 0.f);
    float qp = g[0] * ws0.x + g[1] * ws0.y + g[2] * ws0.z + g[3] * ws0.w
             + g[4] * ws1.x + g[5] * ws1.y + g[6] * ws1.z + g[7] * ws1.w;
    if (half == 0) {
        u16x8 o;
#pragma unroll
        for (int j = 0; j < 8; ++j) o[j] = f2bf(g[j]);
        *(u16x8*)(G2 + ((size_t)i << 8) + cho) = o;
    }
#pragma unroll
    for (int m = 16; m >= 1; m >>= 1) qp += __shfl_xor(qp, m);
    if (lane == 0) {
        tvec[i] = ssum + ni;
        qv[i] = qp;
    }
}

// ---- gemm2: P = G2 @ Wmu (bf16 MFMA, bf16 out), M=12288 K=256 N=64 ----
__global__ __launch_bounds__(256) void k_gemm2(const unsigned short* __restrict__ G2,
                                               const unsigned short* __restrict__ WmuT,
                                               unsigned short* __restrict__ Pb) {
    int wid = threadIdx.x >> 6;
    int lane = threadIdx.x & 63;
    int ln = lane & 15, kg = lane >> 4;
    int rb = blockIdx.x * 128 + wid * 32;
    f32x4 acc[2][4] = {};
    const unsigned short* xa = G2 + (size_t)(rb + ln) * DH + kg * 8;
    const unsigned short* wb = WmuT + (size_t)ln * DH + kg * 8;
    for (int ks = 0; ks < 8; ++ks) {
        int k0 = ks * 32;
        bf16x8 a[2], b[4];
#pragma unroll
        for (int m = 0; m < 2; ++m) a[m] = *(const bf16x8*)(xa + (size_t)m * 16 * DH + k0);
#pragma unroll
        for (int n = 0; n < 4; ++n) b[n] = *(const bf16x8*)(wb + (size_t)n * 16 * DH + k0);
#pragma unroll
        for (int m = 0; m < 2; ++m)
#pragma unroll
            for (int n = 0; n < 4; ++n)
                acc[m][n] = __builtin_amdgcn_mfma_f32_16x16x32_bf16(a[m], b[n], acc[m][n], 0, 0, 0);
    }
#pragma unroll
    for (int m = 0; m < 2; ++m)
#pragma unroll
        for (int n = 0; n < 4; ++n)
#pragma unroll
            for (int r = 0; r < 4; ++r) {
                int row = rb + m * 16 + kg * 4 + r;
                int col = n * 16 + ln;
                Pb[(size_t)row * DZ + col] = f2bf(acc[m][n][r]);
            }
}

// ---- agg2: wave-per-node, 4 edges/iteration (16-lane groups x ushort4). ----
__global__ __launch_bounds__(256) void k_agg2(const unsigned short* __restrict__ Pb,
                                              const float* __restrict__ qv,
                                              const int* __restrict__ rp, const int* __restrict__ ssrc,
                                              const float* __restrict__ norm, const float* __restrict__ tvec,
                                              const float* __restrict__ bmu, const float* __restrict__ bsig,
                                              const float* __restrict__ eps,
                                              float* __restrict__ mus_out, float* __restrict__ logs_out,
                                              unsigned short* __restrict__ Zb) {
    int w = threadIdx.x >> 6;
    int lane = threadIdx.x & 63;
    int grp = lane >> 4, li = lane & 15;
    int i = blockIdx.x * 4 + w;
    int beg = rp[i], end = rp[i + 1];
    int itn = (end - beg + 3) >> 2;
    int co = li * 4;
    float a4[4] = {};
    float qa = 0.f;
#pragma unroll 2
    for (int it = 0; it < itn; ++it) {
        int e = beg + it * 4 + grp;
        if (e < end) {
            int s = ssrc[e];
            ushort4 v = *(const ushort4*)(Pb + ((size_t)s << 6) + co);
            qa += qv[s];
            a4[0] += bf2f(v.x); a4[1] += bf2f(v.y); a4[2] += bf2f(v.z); a4[3] += bf2f(v.w);
        }
    }
    if (grp == 0) {   // self-loop
        ushort4 v = *(const ushort4*)(Pb + ((size_t)i << 6) + co);
        qa += qv[i];
        a4[0] += bf2f(v.x); a4[1] += bf2f(v.y); a4[2] += bf2f(v.z); a4[3] += bf2f(v.w);
    }
#pragma unroll
    for (int j = 0; j < 4; ++j) {
        a4[j] += __shfl_xor(a4[j], 16);
        a4[j] += __shfl_xor(a4[j], 32);
    }
    qa += __shfl_xor(qa, 16);
    qa += __shfl_xor(qa, 32);
    float ni = norm[i], tv = tvec[i];
    float ls = ni * (qa + bsig[0] * tv);
    float sig = expf(0.5f * ls);
    if (lane == 0) logs_out[i] = ls;
    if (lane < 16) {
        const float4 bm = *(const float4*)(bmu + co);
        float4 mu;
        mu.x = ni * (a4[0] + bm.x * tv);
        mu.y = ni * (a4[1] + bm.y * tv);
        mu.z = ni * (a4[2] + bm.z * tv);
        mu.w = ni * (a4[3] + bm.w * tv);
        size_t oidx = ((size_t)i << 6) + co;
        *(float4*)(mus_out + oidx) = mu;
        const float4 ep = *(const float4*)(eps + oidx);
        ushort4 z;
        z.x = f2bf(mu.x + sig * ep.x);
        z.y = f2bf(mu.y + sig * ep.y);
        z.z = f2bf(mu.z + sig * ep.z);
        z.w = f2bf(mu.w + sig * ep.w);
        *(ushort4*)(Zb + oidx) = z;
    }
}

// ---- ZZt = Z @ Z^T. 64x256 tile, 2-phase LDS epilogue, NT stores.
//      Grid SWAPPED: x = col tile (fastest) so concurrent blocks jointly write
//      contiguous rows of one 64-row band -> DRAM page locality. ----
#define LPAD 260
__global__ __launch_bounds__(256) void k_zzt(const unsigned short* __restrict__ Zb, float* __restrict__ out) {
    __shared__ float lds[32 * LPAD];
    int w = threadIdx.x >> 6;
    int lane = threadIdx.x & 63;
    int ln = lane & 15, kg = lane >> 4;
    int rb = blockIdx.y * 64;           // output rows (slow dim)
    int cb = blockIdx.x * 256 + w * 64; // output cols (fast dim), wave-split
    bf16x8 a[4][2], b[4][2];
#pragma unroll
    for (int m = 0; m < 4; ++m)
#pragma unroll
        for (int kc = 0; kc < 2; ++kc)
            a[m][kc] = *(const bf16x8*)(Zb + (size_t)(rb + m * 16 + ln) * DZ + kc * 32 + kg * 8);
#pragma unroll
    for (int n = 0; n < 4; ++n)
#pragma unroll
        for (int kc = 0; kc < 2; ++kc)
            b[n][kc] = *(const bf16x8*)(Zb + (size_t)(cb + n * 16 + ln) * DZ + kc * 32 + kg * 8);
    f32x4 acc[4][4] = {};
#pragma unroll
    for (int m = 0; m < 4; ++m)
#pragma unroll
        for (int n = 0; n < 4; ++n) {
            acc[m][n] = __builtin_amdgcn_mfma_f32_16x16x32_bf16(a[m][0], b[n][0], acc[m][n], 0, 0, 0);
            acc[m][n] = __builtin_amdgcn_mfma_f32_16x16x32_bf16(a[m][1], b[n][1], acc[m][n], 0, 0, 0);
        }
    int c4 = (threadIdx.x & 63) * 4;
    int rw = threadIdx.x >> 6;
    size_t colbase = (size_t)blockIdx.x * 256 + c4;
#pragma unroll
    for (int p = 0; p < 2; ++p) {
        if (p) __syncthreads();
#pragma unroll
        for (int mm = 0; mm < 2; ++mm) {
            int m = p * 2 + mm;
#pragma unroll
            for (int n = 0; n < 4; ++n)
#pragma unroll
                for (int r = 0; r < 4; ++r)
                    lds[(mm * 16 + kg * 4 + r) * LPAD + w * 64 + n * 16 + ln] = acc[m][n][r];
        }
        __syncthreads();
#pragma unroll
        for (int it = 0; it < 8; ++it) {
            int rl = it * 4 + rw;
            f32x4 v = *(const f32x4*)&lds[rl * LPAD + c4];
            __builtin_nontemporal_store(v, (f32x4*)(out + (size_t)(rb + p * 32 + rl) * N_NODES + colbase));
        }
    }
}

extern "C" void kernel_launch(void* const* d_in, const int* in_sizes, int n_in,
                              void* d_out, int out_size, void* d_ws, size_t ws_size,
                              hipStream_t stream) {
    const float* X = (const float*)d_in[0];
    const int* edge = (const int*)d_in[1];
    const float* W1 = (const float*)d_in[2];
    const float* b1 = (const float*)d_in[3];
    const float* Wmu = (const float*)d_in[4];
    const float* bmu = (const float*)d_in[5];
    const float* Wsig = (const float*)d_in[6];
    const float* bsig = (const float*)d_in[7];
    const float* eps = (const float*)d_in[8];

    const int* esrc = edge;
    const int* edst = edge + N_EDGES;

    char* w = (char*)d_ws;
    int* flag = (int*)w;           w += 64;                      // scan-done flag (memset to 0)
    int* deg = (int*)w;            w += (size_t)N_NODES * 4;     // (memset to 0)
    int* cursor = (int*)w;         w += (size_t)N_NODES * 4;
    float* norm = (float*)w;       w += (size_t)N_NODES * 4;
    float* tvec = (float*)w;       w += (size_t)N_NODES * 4;
    float* qv = (float*)w;         w += (size_t)N_NODES * 4;
    int* rowptr = (int*)w;         w += (size_t)(N_NODES + 64) * 4;
    int* ssrc = (int*)w;           w += (size_t)N_EDGES * 4;
    unsigned short* Xb = (unsigned short*)w;   w += (size_t)N_NODES * DIN * 2;
    unsigned short* W1T = (unsigned short*)w;  w += (size_t)DIN * DH * 2;
    unsigned short* WmuT = (unsigned short*)w; w += (size_t)DH * DZ * 2;
    unsigned short* g1 = (unsigned short*)w;   w += (size_t)N_NODES * DH * 2;
    unsigned short* G2 = (unsigned short*)w;   w += (size_t)N_NODES * DH * 2;
    unsigned short* Pb = (unsigned short*)w;   w += (size_t)N_NODES * DZ * 2;
    unsigned short* Zb = (unsigned short*)w;   w += (size_t)N_NODES * DZ * 2;

    float* out_zzt = (float*)d_out;
    float* out_mus = out_zzt + (size_t)N_NODES * N_NODES;
    float* out_logs = out_mus + (size_t)N_NODES * DZ;

    (void)hipMemsetAsync(d_ws, 0, 64 + (size_t)N_NODES * 4, stream);   // flag + deg
    k_prep<<<8256, 256, 0, stream>>>(X, Xb, W1, W1T, Wmu, WmuT, edst, deg);
    k_sg<<<768, 512, 0, stream>>>(Xb, W1T, b1, deg, norm, g1, esrc, edst, rowptr, cursor, ssrc, flag);
    k_agg1<<<N_NODES / 4, 256, 0, stream>>>(g1, rowptr, ssrc, norm, Wsig, G2, tvec, qv);
    k_gemm2<<<N_NODES / 128, 256, 0, stream>>>(G2, WmuT, Pb);
    k_agg2<<<N_NODES / 4, 256, 0, stream>>>(Pb, qv, rowptr, ssrc, norm, tvec, bmu, bsig, eps,
                                            out_mus, out_logs, Zb);
    k_zzt<<<dim3(N_NODES / 256, N_NODES / 64), 256, 0, stream>>>(Zb, out_zzt);
}